// Round 11
// baseline (420.210 us; speedup 1.0000x reference)
//
#include <hip/hip_runtime.h>
#include <cstdint>
#include <cstddef>

#define NNODES 100000
#define NEDGES 1600000
#define FIN    128
#define HID    64
#define NCLS   40
#define BSH    9                                   // 512 nodes per bucket
#define BNODES (1 << BSH)
#define NBUCK  ((NNODES + BNODES - 1) >> BSH)      // 196
#define EPB    8192                                // edges per k_bin block
#define NBINBLK ((NEDGES + EPB - 1) / EPB)         // 196
#define CSR_CAP 12288                              // slots per bucket

typedef __attribute__((ext_vector_type(8))) short bf16x8;
typedef __attribute__((ext_vector_type(16))) float f32x16;

// ---------------- bf16 helpers ----------------
__device__ __forceinline__ uint32_t bf16rne(float f) {
  uint32_t u = __float_as_uint(f);
  return (u + 0x7fffu + ((u >> 16) & 1u)) >> 16;
}
__device__ __forceinline__ float bfu(ushort us) { return __uint_as_float(((uint32_t)us) << 16); }

// ---------------- Threefry-2x32 (JAX-compatible, partitionable) ----------------
__device__ __forceinline__ uint32_t rotl32(uint32_t x, uint32_t r) {
  return (x << r) | (x >> (32u - r));
}

__device__ __forceinline__ void threefry2x32(uint32_t k0, uint32_t k1,
                                             uint32_t c0, uint32_t c1,
                                             uint32_t& o0, uint32_t& o1) {
  const uint32_t ks2 = k0 ^ k1 ^ 0x1BD11BDAu;
  uint32_t x0 = c0 + k0;
  uint32_t x1 = c1 + k1;
#define TF_R(r) { x0 += x1; x1 = rotl32(x1, r); x1 ^= x0; }
  TF_R(13u) TF_R(15u) TF_R(26u) TF_R(6u)
  x0 += k1;  x1 += ks2 + 1u;
  TF_R(17u) TF_R(29u) TF_R(16u) TF_R(24u)
  x0 += ks2; x1 += k0 + 2u;
  TF_R(13u) TF_R(15u) TF_R(26u) TF_R(6u)
  x0 += k0;  x1 += k1 + 3u;
  TF_R(17u) TF_R(29u) TF_R(16u) TF_R(24u)
  x0 += k1;  x1 += ks2 + 4u;
  TF_R(13u) TF_R(15u) TF_R(26u) TF_R(6u)
  x0 += ks2; x1 += k0 + 5u;
#undef TF_R
  o0 = x0; o1 = x1;
}

// ---------------- CSR build (unchanged from round 9) ----------------
__global__ __launch_bounds__(256) void k_initcur(int* __restrict__ gcur) {
  gcur[threadIdx.x] = threadIdx.x * CSR_CAP;
}

__global__ __launch_bounds__(256) void k_bin(const int* __restrict__ row,
                                             const int* __restrict__ col,
                                             int* __restrict__ gcur,
                                             uint32_t* __restrict__ pairs) {
  __shared__ int hcnt[256];
  __shared__ int sc[256];
  __shared__ int lofs[256];
  __shared__ int cur2[256];
  __shared__ int gofs[256];
  __shared__ uint32_t buf[EPB];
  __shared__ unsigned char bid[EPB];
  const int t = threadIdx.x;
  const int e0 = blockIdx.x * EPB;
  const int m = min(EPB, NEDGES - e0);
  hcnt[t] = 0;
  __syncthreads();
  for (int i = t; i < m; i += 256) {
    atomicAdd(&hcnt[col[e0 + i] >> BSH], 1);
  }
  __syncthreads();
  sc[t] = hcnt[t];
  __syncthreads();
  for (int d = 1; d < 256; d <<= 1) {
    int u = (t >= d) ? sc[t - d] : 0;
    __syncthreads();
    sc[t] += u;
    __syncthreads();
  }
  const int ex = sc[t] - hcnt[t];
  lofs[t] = ex;
  cur2[t] = ex;
  if (t < NBUCK) gofs[t] = atomicAdd(&gcur[t], hcnt[t]);
  __syncthreads();
  for (int i = t; i < m; i += 256) {
    const int c = col[e0 + i];
    const int r = row[e0 + i];
    const int b = c >> BSH;
    const int p = atomicAdd(&cur2[b], 1);
    buf[p] = ((uint32_t)r << BSH) | (uint32_t)(c & (BNODES - 1));
    bid[p] = (unsigned char)b;
  }
  __syncthreads();
  for (int i = t; i < m; i += 256) {
    const int b = bid[i];
    pairs[gofs[b] + (i - lofs[b])] = buf[i];
  }
}

__global__ __launch_bounds__(256) void k_bscan(const int* __restrict__ gcur,
                                               int* __restrict__ bbase) {
  __shared__ int sc[256];
  __shared__ int cval[256];
  const int t = threadIdx.x;
  const int c = gcur[t] - t * CSR_CAP;
  cval[t] = c;
  sc[t] = c;
  __syncthreads();
  for (int d = 1; d < 256; d <<= 1) {
    int u = (t >= d) ? sc[t - d] : 0;
    __syncthreads();
    sc[t] += u;
    __syncthreads();
  }
  bbase[t] = sc[t] - cval[t];
}

__global__ __launch_bounds__(256) void k_csr(const uint32_t* __restrict__ pairs,
                                             const int* __restrict__ gcur,
                                             const int* __restrict__ bbase,
                                             int* __restrict__ offs,
                                             float* __restrict__ dis,
                                             int* __restrict__ elist) {
  __shared__ int hist[BNODES];
  __shared__ int ncur[BNODES];
  __shared__ int wsum[4];
  __shared__ int ebuf[CSR_CAP];
  const int b = blockIdx.x, t = threadIdx.x;
  const int nf = b << BSH;
  const int slot0 = b * CSR_CAP;
  const int ne = gcur[b] - slot0;
  const int base = bbase[b];
  hist[2 * t] = 0;
  hist[2 * t + 1] = 0;
  __syncthreads();
  for (int i = t; i < ne; i += 256) {
    atomicAdd(&hist[pairs[slot0 + i] & (BNODES - 1)], 1);
  }
  __syncthreads();
  const int a = hist[2 * t], c = hist[2 * t + 1];
  const int s = a + c;
  const int lane = t & 63, wid = t >> 6;
  int scv = s;
#pragma unroll
  for (int off = 1; off < 64; off <<= 1) {
    int u = __shfl_up(scv, off, 64);
    if (lane >= off) scv += u;
  }
  if (lane == 63) wsum[wid] = scv;
  __syncthreads();
  int wadd = 0;
  for (int w = 0; w < wid; ++w) wadd += wsum[w];
  const int ex = scv - s + wadd;
  const int n0 = nf + 2 * t, n1 = nf + 2 * t + 1;
  if (n0 < NNODES) {
    offs[n0] = base + ex;
    dis[n0] = rsqrtf((float)(a + 1));
  }
  if (n1 < NNODES) {
    offs[n1] = base + ex + a;
    dis[n1] = rsqrtf((float)(c + 1));
  }
  if (b == NBUCK - 1 && t == 0) offs[NNODES] = base + ne;
  ncur[2 * t] = ex;
  ncur[2 * t + 1] = ex + a;
  __syncthreads();
  for (int i = t; i < ne; i += 256) {
    const uint32_t p = pairs[slot0 + i];
    const int n = (int)(p & (BNODES - 1));
    const int sl = atomicAdd(&ncur[n], 1);
    ebuf[sl] = (int)(p >> BSH);
  }
  __syncthreads();
  for (int i = t; i < ne; i += 256) elist[base + i] = ebuf[i];
}

// ---------------- mm1 (MFMA): h1c[ch][r][16] = bf16( (x @ W1) * dis[r] ) -----
__global__ __launch_bounds__(256) void k_mm1(const float* __restrict__ x,
                                             const float* __restrict__ W1,
                                             const float* __restrict__ dis,
                                             ushort* __restrict__ h1c) {
  __shared__ ushort wl[FIN * HID];  // W1 as bf16, row-major [128][64]
  const int t = threadIdx.x;
  for (int i = t; i < FIN * HID; i += 256) wl[i] = (ushort)bf16rne(W1[i]);
  __syncthreads();

  const int lane = t & 63;
  const int wglob = blockIdx.x * 4 + (t >> 6);
  const int r0 = wglob * 64;
  if (r0 >= NNODES) return;
  const int c0 = lane & 31;
  const int hi8 = (lane >> 5) * 8;

  bf16x8 wb0[8], wb1[8];
#pragma unroll
  for (int ks = 0; ks < 8; ++ks) {
#pragma unroll
    for (int i = 0; i < 8; ++i) {
      const int k = ks * 16 + hi8 + i;
      wb0[ks][i] = (short)wl[k * HID + c0];
      wb1[ks][i] = (short)wl[k * HID + 32 + c0];
    }
  }

  const int ra = min(r0 + c0, NNODES - 1);
  const int rb = min(r0 + 32 + c0, NNODES - 1);
  f32x16 acc00 = {0}, acc01 = {0}, acc10 = {0}, acc11 = {0};
#pragma unroll
  for (int ks = 0; ks < 8; ++ks) {
    const int k0 = ks * 16 + hi8;
    const float4 fa0 = *reinterpret_cast<const float4*>(x + (size_t)ra * FIN + k0);
    const float4 fa1 = *reinterpret_cast<const float4*>(x + (size_t)ra * FIN + k0 + 4);
    const float4 fb0 = *reinterpret_cast<const float4*>(x + (size_t)rb * FIN + k0);
    const float4 fb1 = *reinterpret_cast<const float4*>(x + (size_t)rb * FIN + k0 + 4);
    bf16x8 a0, a1;
    a0[0] = (short)bf16rne(fa0.x); a0[1] = (short)bf16rne(fa0.y);
    a0[2] = (short)bf16rne(fa0.z); a0[3] = (short)bf16rne(fa0.w);
    a0[4] = (short)bf16rne(fa1.x); a0[5] = (short)bf16rne(fa1.y);
    a0[6] = (short)bf16rne(fa1.z); a0[7] = (short)bf16rne(fa1.w);
    a1[0] = (short)bf16rne(fb0.x); a1[1] = (short)bf16rne(fb0.y);
    a1[2] = (short)bf16rne(fb0.z); a1[3] = (short)bf16rne(fb0.w);
    a1[4] = (short)bf16rne(fb1.x); a1[5] = (short)bf16rne(fb1.y);
    a1[6] = (short)bf16rne(fb1.z); a1[7] = (short)bf16rne(fb1.w);
    acc00 = __builtin_amdgcn_mfma_f32_32x32x16_bf16(a0, wb0[ks], acc00, 0, 0, 0);
    acc01 = __builtin_amdgcn_mfma_f32_32x32x16_bf16(a0, wb1[ks], acc01, 0, 0, 0);
    acc10 = __builtin_amdgcn_mfma_f32_32x32x16_bf16(a1, wb0[ks], acc10, 0, 0, 0);
    acc11 = __builtin_amdgcn_mfma_f32_32x32x16_bf16(a1, wb1[ks], acc11, 0, 0, 0);
  }

  const int rrb = 4 * (lane >> 5);
  const int chA = c0 >> 4, flA = c0 & 15;  // feats c0 -> chunk 0/1; 32+c0 -> 2/3
#pragma unroll
  for (int reg = 0; reg < 16; ++reg) {
    const int rr = (reg & 3) + 8 * (reg >> 2) + rrb;
    const int r_a = r0 + rr;
    const int r_b = r0 + 32 + rr;
    if (r_a < NNODES) {
      const float d = dis[r_a];
      h1c[((size_t)chA * NNODES + r_a) * 16 + flA]       = (ushort)bf16rne(acc00[reg] * d);
      h1c[((size_t)(2 + chA) * NNODES + r_a) * 16 + flA] = (ushort)bf16rne(acc01[reg] * d);
    }
    if (r_b < NNODES) {
      const float d = dis[r_b];
      h1c[((size_t)chA * NNODES + r_b) * 16 + flA]       = (ushort)bf16rne(acc10[reg] * d);
      h1c[((size_t)(2 + chA) * NNODES + r_b) * 16 + flA] = (ushort)bf16rne(acc11[reg] * d);
    }
  }
}

// ---------------- mm2 (MFMA): gs_c[ch][r][16] = bf16( (h2 @ W2) * dis[r] ) ---
__global__ __launch_bounds__(256) void k_mm2(const ushort* __restrict__ h2c,
                                             const float* __restrict__ W2,
                                             const float* __restrict__ dis,
                                             ushort* __restrict__ gs_c) {
  __shared__ ushort wl[HID * 64];  // [64][64], cols >= 40 zero
  const int t = threadIdx.x;
  for (int i = t; i < HID * 64; i += 256) {
    const int k = i >> 6, c = i & 63;
    wl[i] = (c < NCLS) ? (ushort)bf16rne(W2[k * NCLS + c]) : (ushort)0;
  }
  __syncthreads();

  const int lane = t & 63;
  const int wglob = blockIdx.x * 4 + (t >> 6);
  const int r0 = wglob * 64;
  if (r0 >= NNODES) return;
  const int c0 = lane & 31;
  const int hi8 = (lane >> 5) * 8;

  bf16x8 wb0[4], wb1[4];
#pragma unroll
  for (int ks = 0; ks < 4; ++ks) {
#pragma unroll
    for (int i = 0; i < 8; ++i) {
      const int k = ks * 16 + hi8 + i;
      wb0[ks][i] = (short)wl[k * 64 + c0];
      wb1[ks][i] = (short)wl[k * 64 + 32 + c0];
    }
  }

  const int ra = min(r0 + c0, NNODES - 1);
  const int rb = min(r0 + 32 + c0, NNODES - 1);
  f32x16 acc00 = {0}, acc01 = {0}, acc10 = {0}, acc11 = {0};
#pragma unroll
  for (int ks = 0; ks < 4; ++ks) {
    // h2 row-chunked: feats ks*16+hi8..+8 live at h2c[ks][row][hi8..hi8+8]
    const bf16x8 a0 = *reinterpret_cast<const bf16x8*>(h2c + ((size_t)ks * NNODES + ra) * 16 + hi8);
    const bf16x8 a1 = *reinterpret_cast<const bf16x8*>(h2c + ((size_t)ks * NNODES + rb) * 16 + hi8);
    acc00 = __builtin_amdgcn_mfma_f32_32x32x16_bf16(a0, wb0[ks], acc00, 0, 0, 0);
    acc01 = __builtin_amdgcn_mfma_f32_32x32x16_bf16(a0, wb1[ks], acc01, 0, 0, 0);
    acc10 = __builtin_amdgcn_mfma_f32_32x32x16_bf16(a1, wb0[ks], acc10, 0, 0, 0);
    acc11 = __builtin_amdgcn_mfma_f32_32x32x16_bf16(a1, wb1[ks], acc11, 0, 0, 0);
  }

  const int rrb = 4 * (lane >> 5);
  const int chA = c0 >> 4, flA = c0 & 15;
#pragma unroll
  for (int reg = 0; reg < 16; ++reg) {
    const int rr = (reg & 3) + 8 * (reg >> 2) + rrb;
    const int r_a = r0 + rr;
    const int r_b = r0 + 32 + rr;
    if (r_a < NNODES) {
      const float d = dis[r_a];
      gs_c[((size_t)chA * NNODES + r_a) * 16 + flA] = (ushort)bf16rne(acc00[reg] * d);
      if (c0 < 8)       gs_c[((size_t)2 * NNODES + r_a) * 16 + c0] = (ushort)bf16rne(acc01[reg] * d);
      else if (c0 < 16) gs_c[((size_t)2 * NNODES + r_a) * 16 + c0] = 0;  // pad feats 40..47
    }
    if (r_b < NNODES) {
      const float d = dis[r_b];
      gs_c[((size_t)chA * NNODES + r_b) * 16 + flA] = (ushort)bf16rne(acc10[reg] * d);
      if (c0 < 8)       gs_c[((size_t)2 * NNODES + r_b) * 16 + c0] = (ushort)bf16rne(acc11[reg] * d);
      else if (c0 < 16) gs_c[((size_t)2 * NNODES + r_b) * 16 + c0] = 0;
    }
  }
}

// ---------------- chunked gather-aggregate, layer 1 ----------------
// one wave per node per 16-feature chunk; q=lane>>4 edge slot, fl=lane&15 feat
__global__ __launch_bounds__(256) void k_agg1c(const ushort* __restrict__ h1c,
                                               const int* __restrict__ elist,
                                               const int* __restrict__ offs,
                                               const float* __restrict__ dis,
                                               const float* __restrict__ b1,
                                               ushort* __restrict__ h2c,
                                               int p) {
  const int gid = blockIdx.x * 256 + threadIdx.x;
  const int node = gid >> 6;
  const int lane = gid & 63;
  if (node >= NNODES) return;
  const int q = lane >> 4, fl = lane & 15;
  const ushort* tab = h1c + (size_t)p * NNODES * 16;
  const int base = offs[node];
  const int n = offs[node + 1] - base;
  float acc0 = (q == 0) ? bfu(tab[(size_t)node * 16 + fl]) : 0.f;  // self
  float acc1 = 0.f, acc2 = 0.f, acc3 = 0.f;
  for (int k0 = 0; k0 < n; k0 += 64) {
    const int mm = min(64, n - k0);
    int srcl = 0;
    if (lane < mm) srcl = __builtin_nontemporal_load(elist + base + k0 + lane);
    for (int j = 0; j < mm; j += 16) {
      const int e0 = j + q, e1 = j + 4 + q, e2 = j + 8 + q, e3 = j + 12 + q;
      const int s0 = __shfl(srcl, e0, 64);
      const int s1 = __shfl(srcl, e1, 64);
      const int s2 = __shfl(srcl, e2, 64);
      const int s3 = __shfl(srcl, e3, 64);
      if (e0 < mm) acc0 += bfu(tab[(size_t)s0 * 16 + fl]);
      if (e1 < mm) acc1 += bfu(tab[(size_t)s1 * 16 + fl]);
      if (e2 < mm) acc2 += bfu(tab[(size_t)s2 * 16 + fl]);
      if (e3 < mm) acc3 += bfu(tab[(size_t)s3 * 16 + fl]);
    }
  }
  float a = (acc0 + acc1) + (acc2 + acc3);
  a += __shfl_xor(a, 16, 64);
  a += __shfl_xor(a, 32, 64);
  if (lane < 16) {
    const int f = (p << 4) + fl;
    float v = a * dis[node] + b1[f];
    v = fmaxf(v, 0.0f);
    const uint32_t idx = (uint32_t)node * HID + f;
    uint32_t o0, o1;
    threefry2x32(0u, 42u, 0u, idx, o0, o1);
    const uint32_t bits = o0 ^ o1;
    const float u = __uint_as_float((bits >> 9) | 0x3f800000u) - 1.0f;
    const float keepf = (float)(1.0 - 0.4144);
    const float val = (u < keepf) ? v / keepf : 0.0f;
    h2c[((size_t)p * NNODES + node) * 16 + fl] = (ushort)bf16rne(val);
  }
}

// ---------------- chunked gather-aggregate, layer 2 (partial logits) ----------
__global__ __launch_bounds__(256) void k_agg2c(const ushort* __restrict__ gs_c,
                                               const int* __restrict__ elist,
                                               const int* __restrict__ offs,
                                               const float* __restrict__ dis,
                                               const float* __restrict__ b2,
                                               float* __restrict__ logits,
                                               int p) {
  const int gid = blockIdx.x * 256 + threadIdx.x;
  const int node = gid >> 6;
  const int lane = gid & 63;
  if (node >= NNODES) return;
  const int q = lane >> 4, fl = lane & 15;
  const ushort* tab = gs_c + (size_t)p * NNODES * 16;
  const int base = offs[node];
  const int n = offs[node + 1] - base;
  float acc0 = (q == 0) ? bfu(tab[(size_t)node * 16 + fl]) : 0.f;  // self
  float acc1 = 0.f, acc2 = 0.f, acc3 = 0.f;
  for (int k0 = 0; k0 < n; k0 += 64) {
    const int mm = min(64, n - k0);
    int srcl = 0;
    if (lane < mm) srcl = __builtin_nontemporal_load(elist + base + k0 + lane);
    for (int j = 0; j < mm; j += 16) {
      const int e0 = j + q, e1 = j + 4 + q, e2 = j + 8 + q, e3 = j + 12 + q;
      const int s0 = __shfl(srcl, e0, 64);
      const int s1 = __shfl(srcl, e1, 64);
      const int s2 = __shfl(srcl, e2, 64);
      const int s3 = __shfl(srcl, e3, 64);
      if (e0 < mm) acc0 += bfu(tab[(size_t)s0 * 16 + fl]);
      if (e1 < mm) acc1 += bfu(tab[(size_t)s1 * 16 + fl]);
      if (e2 < mm) acc2 += bfu(tab[(size_t)s2 * 16 + fl]);
      if (e3 < mm) acc3 += bfu(tab[(size_t)s3 * 16 + fl]);
    }
  }
  float a = (acc0 + acc1) + (acc2 + acc3);
  a += __shfl_xor(a, 16, 64);
  a += __shfl_xor(a, 32, 64);
  if (lane < 16) {
    const int f = (p << 4) + fl;
    if (f < NCLS) logits[((size_t)p * NNODES + node) * 16 + fl] = a * dis[node] + b2[f];
  }
}

// ---------------- log_softmax from chunked logits ----------------
__global__ __launch_bounds__(256) void k_lsm(const float* __restrict__ logits,
                                             float* __restrict__ out) {
  const int gid = blockIdx.x * 256 + threadIdx.x;
  const int node = gid >> 6;
  const int lane = gid & 63;
  if (node >= NNODES) return;
  float v = -INFINITY;
  if (lane < NCLS) {
    v = logits[((size_t)(lane >> 4) * NNODES + node) * 16 + (lane & 15)];
  }
  float mx = v;
#pragma unroll
  for (int off = 32; off > 0; off >>= 1) mx = fmaxf(mx, __shfl_xor(mx, off, 64));
  float e = (lane < NCLS) ? expf(v - mx) : 0.0f;
  float s = e;
#pragma unroll
  for (int off = 32; off > 0; off >>= 1) s += __shfl_xor(s, off, 64);
  const float ls = logf(s);
  if (lane < NCLS) out[(size_t)node * NCLS + lane] = v - mx - ls;
}

// ---------------- launch ----------------
extern "C" void kernel_launch(void* const* d_in, const int* in_sizes, int n_in,
                              void* d_out, int out_size, void* d_ws, size_t ws_size,
                              hipStream_t stream) {
  const float* x  = (const float*)d_in[0];
  const int*   ei = (const int*)d_in[1];
  const float* W1 = (const float*)d_in[2];
  const float* b1 = (const float*)d_in[3];
  const float* W2 = (const float*)d_in[4];
  const float* b2 = (const float*)d_in[5];
  float* out = (float*)d_out;

  const int* row = ei;           // edge_index[0]  (source)
  const int* col = ei + NEDGES;  // edge_index[1]  (destination)

  float* ws  = (float*)d_ws;
  float* dis = ws;                                      // N f32
  ushort* h1c = (ushort*)(ws + 100352);                 // [4][N][16] bf16 = 12.8MB
  ushort* h2c = h1c + (size_t)4 * NNODES * 16;          // [4][N][16] bf16 = 12.8MB
  float* logits = (float*)(h2c + (size_t)4 * NNODES * 16);  // [3][N][16] f32 = 19.2MB
  int* offs  = (int*)(logits + (size_t)3 * NNODES * 16);    // N+1
  int* gcur  = offs + NNODES + 64;                      // 256
  int* bbase = gcur + 256;                              // 256
  int* elist = bbase + 256;                             // E
  uint32_t* pairs = (uint32_t*)h2c;  // alias: consumed by k_csr before agg1 writes h2c
  ushort* gs_c = h1c;                // alias: h1c dead after agg1 passes

  const dim3 B(256);
  const int GNW = (NNODES * 64 + 255) / 256;     // wave per node
  const int GMM = (NNODES + 255) / 256;          // 64 rows/wave * 4 waves

  // CSR build (bin -> bucket scan -> per-bucket sort)
  k_initcur<<<dim3(1), B, 0, stream>>>(gcur);
  k_bin  <<<dim3(NBINBLK), B, 0, stream>>>(row, col, gcur, pairs);
  k_bscan<<<dim3(1), B, 0, stream>>>(gcur, bbase);
  k_csr  <<<dim3(NBUCK), B, 0, stream>>>(pairs, gcur, bbase, offs, dis, elist);

  // layer 1: transform then chunked aggregation (L2-resident 3.2MB tables)
  k_mm1<<<dim3(GMM), B, 0, stream>>>(x, W1, dis, h1c);
  for (int p = 0; p < 4; ++p)
    k_agg1c<<<dim3(GNW), B, 0, stream>>>(h1c, elist, offs, dis, b1, h2c, p);

  // layer 2
  k_mm2<<<dim3(GMM), B, 0, stream>>>(h2c, W2, dis, gs_c);
  for (int p = 0; p < 3; ++p)
    k_agg2c<<<dim3(GNW), B, 0, stream>>>(gs_c, elist, offs, dis, b2, logits, p);
  k_lsm<<<dim3(GNW), B, 0, stream>>>(logits, out);
}

// Round 12
// 200.573 us; speedup vs baseline: 2.0950x; 2.0950x over previous
//
#include <hip/hip_runtime.h>
#include <cstdint>
#include <cstddef>

#define NNODES 100000
#define NEDGES 1600000
#define FIN    128
#define HID    64
#define NCLS   40
#define BSH    9                                   // 512 nodes per bucket
#define BNODES (1 << BSH)
#define NBUCK  ((NNODES + BNODES - 1) >> BSH)      // 196
#define EPB    8192                                // edges per k_bin block
#define NBINBLK ((NEDGES + EPB - 1) / EPB)         // 196
#define CSR_CAP 12288                              // slots per bucket

typedef __attribute__((ext_vector_type(8))) short bf16x8;
typedef __attribute__((ext_vector_type(16))) float f32x16;

// ---------------- bf16 helpers ----------------
__device__ __forceinline__ uint32_t bf16rne(float f) {
  uint32_t u = __float_as_uint(f);
  return (u + 0x7fffu + ((u >> 16) & 1u)) >> 16;
}
__device__ __forceinline__ float bfu(ushort us) { return __uint_as_float(((uint32_t)us) << 16); }
__device__ __forceinline__ float bflo(uint32_t u) { return __uint_as_float(u << 16); }
__device__ __forceinline__ float bfhi(uint32_t u) { return __uint_as_float(u & 0xffff0000u); }
__device__ __forceinline__ uint32_t pk2(float a, float b) {
  return bf16rne(a) | (bf16rne(b) << 16);
}

// ---------------- Threefry-2x32 (JAX-compatible, partitionable) ----------------
__device__ __forceinline__ uint32_t rotl32(uint32_t x, uint32_t r) {
  return (x << r) | (x >> (32u - r));
}

__device__ __forceinline__ void threefry2x32(uint32_t k0, uint32_t k1,
                                             uint32_t c0, uint32_t c1,
                                             uint32_t& o0, uint32_t& o1) {
  const uint32_t ks2 = k0 ^ k1 ^ 0x1BD11BDAu;
  uint32_t x0 = c0 + k0;
  uint32_t x1 = c1 + k1;
#define TF_R(r) { x0 += x1; x1 = rotl32(x1, r); x1 ^= x0; }
  TF_R(13u) TF_R(15u) TF_R(26u) TF_R(6u)
  x0 += k1;  x1 += ks2 + 1u;
  TF_R(17u) TF_R(29u) TF_R(16u) TF_R(24u)
  x0 += ks2; x1 += k0 + 2u;
  TF_R(13u) TF_R(15u) TF_R(26u) TF_R(6u)
  x0 += k0;  x1 += k1 + 3u;
  TF_R(17u) TF_R(29u) TF_R(16u) TF_R(24u)
  x0 += k1;  x1 += ks2 + 4u;
  TF_R(13u) TF_R(15u) TF_R(26u) TF_R(6u)
  x0 += ks2; x1 += k0 + 5u;
#undef TF_R
  o0 = x0; o1 = x1;
}

// ---------------- CSR build (round-9 version, measured fine) ----------------
__global__ __launch_bounds__(256) void k_initcur(int* __restrict__ gcur) {
  gcur[threadIdx.x] = threadIdx.x * CSR_CAP;
}

__global__ __launch_bounds__(256) void k_bin(const int* __restrict__ row,
                                             const int* __restrict__ col,
                                             int* __restrict__ gcur,
                                             uint32_t* __restrict__ pairs) {
  __shared__ int hcnt[256];
  __shared__ int sc[256];
  __shared__ int lofs[256];
  __shared__ int cur2[256];
  __shared__ int gofs[256];
  __shared__ uint32_t buf[EPB];
  __shared__ unsigned char bid[EPB];
  const int t = threadIdx.x;
  const int e0 = blockIdx.x * EPB;
  const int m = min(EPB, NEDGES - e0);
  hcnt[t] = 0;
  __syncthreads();
  for (int i = t; i < m; i += 256) {
    atomicAdd(&hcnt[col[e0 + i] >> BSH], 1);
  }
  __syncthreads();
  sc[t] = hcnt[t];
  __syncthreads();
  for (int d = 1; d < 256; d <<= 1) {
    int u = (t >= d) ? sc[t - d] : 0;
    __syncthreads();
    sc[t] += u;
    __syncthreads();
  }
  const int ex = sc[t] - hcnt[t];
  lofs[t] = ex;
  cur2[t] = ex;
  if (t < NBUCK) gofs[t] = atomicAdd(&gcur[t], hcnt[t]);
  __syncthreads();
  for (int i = t; i < m; i += 256) {
    const int c = col[e0 + i];
    const int r = row[e0 + i];
    const int b = c >> BSH;
    const int p = atomicAdd(&cur2[b], 1);
    buf[p] = ((uint32_t)r << BSH) | (uint32_t)(c & (BNODES - 1));
    bid[p] = (unsigned char)b;
  }
  __syncthreads();
  for (int i = t; i < m; i += 256) {
    const int b = bid[i];
    pairs[gofs[b] + (i - lofs[b])] = buf[i];
  }
}

__global__ __launch_bounds__(256) void k_bscan(const int* __restrict__ gcur,
                                               int* __restrict__ bbase) {
  __shared__ int sc[256];
  __shared__ int cval[256];
  const int t = threadIdx.x;
  const int c = gcur[t] - t * CSR_CAP;
  cval[t] = c;
  sc[t] = c;
  __syncthreads();
  for (int d = 1; d < 256; d <<= 1) {
    int u = (t >= d) ? sc[t - d] : 0;
    __syncthreads();
    sc[t] += u;
    __syncthreads();
  }
  bbase[t] = sc[t] - cval[t];
}

__global__ __launch_bounds__(256) void k_csr(const uint32_t* __restrict__ pairs,
                                             const int* __restrict__ gcur,
                                             const int* __restrict__ bbase,
                                             int* __restrict__ offs,
                                             float* __restrict__ dis,
                                             int* __restrict__ elist) {
  __shared__ int hist[BNODES];
  __shared__ int ncur[BNODES];
  __shared__ int wsum[4];
  __shared__ int ebuf[CSR_CAP];
  const int b = blockIdx.x, t = threadIdx.x;
  const int nf = b << BSH;
  const int slot0 = b * CSR_CAP;
  const int ne = gcur[b] - slot0;
  const int base = bbase[b];
  hist[2 * t] = 0;
  hist[2 * t + 1] = 0;
  __syncthreads();
  for (int i = t; i < ne; i += 256) {
    atomicAdd(&hist[pairs[slot0 + i] & (BNODES - 1)], 1);
  }
  __syncthreads();
  const int a = hist[2 * t], c = hist[2 * t + 1];
  const int s = a + c;
  const int lane = t & 63, wid = t >> 6;
  int scv = s;
#pragma unroll
  for (int off = 1; off < 64; off <<= 1) {
    int u = __shfl_up(scv, off, 64);
    if (lane >= off) scv += u;
  }
  if (lane == 63) wsum[wid] = scv;
  __syncthreads();
  int wadd = 0;
  for (int w = 0; w < wid; ++w) wadd += wsum[w];
  const int ex = scv - s + wadd;
  const int n0 = nf + 2 * t, n1 = nf + 2 * t + 1;
  if (n0 < NNODES) {
    offs[n0] = base + ex;
    dis[n0] = rsqrtf((float)(a + 1));
  }
  if (n1 < NNODES) {
    offs[n1] = base + ex + a;
    dis[n1] = rsqrtf((float)(c + 1));
  }
  if (b == NBUCK - 1 && t == 0) offs[NNODES] = base + ne;
  ncur[2 * t] = ex;
  ncur[2 * t + 1] = ex + a;
  __syncthreads();
  for (int i = t; i < ne; i += 256) {
    const uint32_t p = pairs[slot0 + i];
    const int n = (int)(p & (BNODES - 1));
    const int sl = atomicAdd(&ncur[n], 1);
    ebuf[sl] = (int)(p >> BSH);
  }
  __syncthreads();
  for (int i = t; i < ne; i += 256) elist[base + i] = ebuf[i];
}

// ---------------- mm1 (MFMA): h1s = bf16( (x @ W1) * dis[row] ) --------------
__global__ __launch_bounds__(256) void k_mm1(const float* __restrict__ x,
                                             const float* __restrict__ W1,
                                             const float* __restrict__ dis,
                                             ushort* __restrict__ h1s) {
  __shared__ ushort wl[FIN * HID];  // W1 as bf16, row-major [128][64]
  const int t = threadIdx.x;
  for (int i = t; i < FIN * HID; i += 256) wl[i] = (ushort)bf16rne(W1[i]);
  __syncthreads();

  const int lane = t & 63;
  const int wglob = blockIdx.x * 4 + (t >> 6);
  const int r0 = wglob * 64;
  if (r0 >= NNODES) return;
  const int c0 = lane & 31;
  const int hi8 = (lane >> 5) * 8;

  bf16x8 wb0[8], wb1[8];
#pragma unroll
  for (int ks = 0; ks < 8; ++ks) {
#pragma unroll
    for (int i = 0; i < 8; ++i) {
      const int k = ks * 16 + hi8 + i;
      wb0[ks][i] = (short)wl[k * HID + c0];
      wb1[ks][i] = (short)wl[k * HID + 32 + c0];
    }
  }

  const int ra = min(r0 + c0, NNODES - 1);
  const int rb = min(r0 + 32 + c0, NNODES - 1);
  f32x16 acc00 = {0}, acc01 = {0}, acc10 = {0}, acc11 = {0};
#pragma unroll
  for (int ks = 0; ks < 8; ++ks) {
    const int k0 = ks * 16 + hi8;
    const float4 fa0 = *reinterpret_cast<const float4*>(x + (size_t)ra * FIN + k0);
    const float4 fa1 = *reinterpret_cast<const float4*>(x + (size_t)ra * FIN + k0 + 4);
    const float4 fb0 = *reinterpret_cast<const float4*>(x + (size_t)rb * FIN + k0);
    const float4 fb1 = *reinterpret_cast<const float4*>(x + (size_t)rb * FIN + k0 + 4);
    bf16x8 a0, a1;
    a0[0] = (short)bf16rne(fa0.x); a0[1] = (short)bf16rne(fa0.y);
    a0[2] = (short)bf16rne(fa0.z); a0[3] = (short)bf16rne(fa0.w);
    a0[4] = (short)bf16rne(fa1.x); a0[5] = (short)bf16rne(fa1.y);
    a0[6] = (short)bf16rne(fa1.z); a0[7] = (short)bf16rne(fa1.w);
    a1[0] = (short)bf16rne(fb0.x); a1[1] = (short)bf16rne(fb0.y);
    a1[2] = (short)bf16rne(fb0.z); a1[3] = (short)bf16rne(fb0.w);
    a1[4] = (short)bf16rne(fb1.x); a1[5] = (short)bf16rne(fb1.y);
    a1[6] = (short)bf16rne(fb1.z); a1[7] = (short)bf16rne(fb1.w);
    acc00 = __builtin_amdgcn_mfma_f32_32x32x16_bf16(a0, wb0[ks], acc00, 0, 0, 0);
    acc01 = __builtin_amdgcn_mfma_f32_32x32x16_bf16(a0, wb1[ks], acc01, 0, 0, 0);
    acc10 = __builtin_amdgcn_mfma_f32_32x32x16_bf16(a1, wb0[ks], acc10, 0, 0, 0);
    acc11 = __builtin_amdgcn_mfma_f32_32x32x16_bf16(a1, wb1[ks], acc11, 0, 0, 0);
  }

  const int rrb = 4 * (lane >> 5);
#pragma unroll
  for (int reg = 0; reg < 16; ++reg) {
    const int rr = (reg & 3) + 8 * (reg >> 2) + rrb;
    const int r_a = r0 + rr;
    const int r_b = r0 + 32 + rr;
    if (r_a < NNODES) {
      const float d = dis[r_a];
      h1s[(size_t)r_a * HID + c0]      = (ushort)bf16rne(acc00[reg] * d);
      h1s[(size_t)r_a * HID + 32 + c0] = (ushort)bf16rne(acc01[reg] * d);
    }
    if (r_b < NNODES) {
      const float d = dis[r_b];
      h1s[(size_t)r_b * HID + c0]      = (ushort)bf16rne(acc10[reg] * d);
      h1s[(size_t)r_b * HID + 32 + c0] = (ushort)bf16rne(acc11[reg] * d);
    }
  }
}

// ---------------- mm2 (MFMA): gs = bf16( (h2 @ W2) * dis[row] ) --------------
__global__ __launch_bounds__(256) void k_mm2(const ushort* __restrict__ h2,
                                             const float* __restrict__ W2,
                                             const float* __restrict__ dis,
                                             ushort* __restrict__ gs) {
  __shared__ ushort wl[HID * 64];  // [64][64], cols >= 40 zero
  const int t = threadIdx.x;
  for (int i = t; i < HID * 64; i += 256) {
    const int k = i >> 6, c = i & 63;
    wl[i] = (c < NCLS) ? (ushort)bf16rne(W2[k * NCLS + c]) : (ushort)0;
  }
  __syncthreads();

  const int lane = t & 63;
  const int wglob = blockIdx.x * 4 + (t >> 6);
  const int r0 = wglob * 64;
  if (r0 >= NNODES) return;
  const int c0 = lane & 31;
  const int hi8 = (lane >> 5) * 8;

  bf16x8 wb0[4], wb1[4];
#pragma unroll
  for (int ks = 0; ks < 4; ++ks) {
#pragma unroll
    for (int i = 0; i < 8; ++i) {
      const int k = ks * 16 + hi8 + i;
      wb0[ks][i] = (short)wl[k * 64 + c0];
      wb1[ks][i] = (short)wl[k * 64 + 32 + c0];
    }
  }

  const int ra = min(r0 + c0, NNODES - 1);
  const int rb = min(r0 + 32 + c0, NNODES - 1);
  f32x16 acc00 = {0}, acc01 = {0}, acc10 = {0}, acc11 = {0};
#pragma unroll
  for (int ks = 0; ks < 4; ++ks) {
    const int k0 = ks * 16 + hi8;
    const bf16x8 a0 = *reinterpret_cast<const bf16x8*>(h2 + (size_t)ra * HID + k0);
    const bf16x8 a1 = *reinterpret_cast<const bf16x8*>(h2 + (size_t)rb * HID + k0);
    acc00 = __builtin_amdgcn_mfma_f32_32x32x16_bf16(a0, wb0[ks], acc00, 0, 0, 0);
    acc01 = __builtin_amdgcn_mfma_f32_32x32x16_bf16(a0, wb1[ks], acc01, 0, 0, 0);
    acc10 = __builtin_amdgcn_mfma_f32_32x32x16_bf16(a1, wb0[ks], acc10, 0, 0, 0);
    acc11 = __builtin_amdgcn_mfma_f32_32x32x16_bf16(a1, wb1[ks], acc11, 0, 0, 0);
  }

  const int rrb = 4 * (lane >> 5);
  const bool c1ok = c0 < (NCLS - 32);  // cols 32..39 only
#pragma unroll
  for (int reg = 0; reg < 16; ++reg) {
    const int rr = (reg & 3) + 8 * (reg >> 2) + rrb;
    const int r_a = r0 + rr;
    const int r_b = r0 + 32 + rr;
    if (r_a < NNODES) {
      const float d = dis[r_a];
      gs[(size_t)r_a * NCLS + c0] = (ushort)bf16rne(acc00[reg] * d);
      if (c1ok) gs[(size_t)r_a * NCLS + 32 + c0] = (ushort)bf16rne(acc01[reg] * d);
    }
    if (r_b < NNODES) {
      const float d = dis[r_b];
      gs[(size_t)r_b * NCLS + c0] = (ushort)bf16rne(acc10[reg] * d);
      if (c1ok) gs[(size_t)r_b * NCLS + 32 + c0] = (ushort)bf16rne(acc11[reg] * d);
    }
  }
}

// ---------------- gather-aggregate layer 1 (uint-pair loads, 2 edge slots) ----
// lane = (q=lane>>5 edge slot, fl=lane&31 uint-feature pair). Per edge: 32
// lane-loads of 4B (2 bf16) instead of 64 of 2B -- half the load/shfl instrs.
__global__ __launch_bounds__(256) void k_agg1(const uint32_t* __restrict__ h1u,
                                              const int* __restrict__ elist,
                                              const int* __restrict__ offs,
                                              const float* __restrict__ dis,
                                              const float* __restrict__ b1,
                                              uint32_t* __restrict__ h2u) {
  const int gid = blockIdx.x * 256 + threadIdx.x;
  const int node = gid >> 6;
  const int lane = gid & 63;
  if (node >= NNODES) return;
  const int fl = lane & 31, q = lane >> 5;
  const int base = offs[node];
  const int n = offs[node + 1] - base;
  float lo0 = 0.f, hi0 = 0.f, lo1 = 0.f, hi1 = 0.f;
  float lo2 = 0.f, hi2 = 0.f, lo3 = 0.f, hi3 = 0.f;
  if (q == 0) {  // self term
    const uint32_t u = h1u[(size_t)node * 32 + fl];
    lo0 = bflo(u); hi0 = bfhi(u);
  }
  for (int k0 = 0; k0 < n; k0 += 64) {
    const int m = min(64, n - k0);
    int srcl = 0;
    if (lane < m) srcl = elist[base + k0 + lane];
    for (int j = 0; j < m; j += 8) {
      const int e0 = j + q, e1 = j + 2 + q, e2 = j + 4 + q, e3 = j + 6 + q;
      const int s0 = __shfl(srcl, e0, 64);
      const int s1 = __shfl(srcl, e1, 64);
      const int s2 = __shfl(srcl, e2, 64);
      const int s3 = __shfl(srcl, e3, 64);
      const uint32_t u0 = (e0 < m) ? h1u[(size_t)s0 * 32 + fl] : 0u;
      const uint32_t u1 = (e1 < m) ? h1u[(size_t)s1 * 32 + fl] : 0u;
      const uint32_t u2 = (e2 < m) ? h1u[(size_t)s2 * 32 + fl] : 0u;
      const uint32_t u3 = (e3 < m) ? h1u[(size_t)s3 * 32 + fl] : 0u;
      lo0 += bflo(u0); hi0 += bfhi(u0);
      lo1 += bflo(u1); hi1 += bfhi(u1);
      lo2 += bflo(u2); hi2 += bfhi(u2);
      lo3 += bflo(u3); hi3 += bfhi(u3);
    }
  }
  float alo = (lo0 + lo1) + (lo2 + lo3);
  float ahi = (hi0 + hi1) + (hi2 + hi3);
  alo += __shfl_xor(alo, 32, 64);
  ahi += __shfl_xor(ahi, 32, 64);
  if (lane < 32) {
    const float d = dis[node];
    const int f0 = fl * 2;
    float v0 = fmaxf(alo * d + b1[f0], 0.0f);
    float v1 = fmaxf(ahi * d + b1[f0 + 1], 0.0f);
    const uint32_t idx0 = (uint32_t)node * HID + f0;
    uint32_t a0, a1, c0, c1;
    threefry2x32(0u, 42u, 0u, idx0, a0, a1);
    threefry2x32(0u, 42u, 0u, idx0 + 1, c0, c1);
    const float u0 = __uint_as_float(((a0 ^ a1) >> 9) | 0x3f800000u) - 1.0f;
    const float u1 = __uint_as_float(((c0 ^ c1) >> 9) | 0x3f800000u) - 1.0f;
    const float keepf = (float)(1.0 - 0.4144);
    const float r0 = (u0 < keepf) ? v0 / keepf : 0.0f;
    const float r1 = (u1 < keepf) ? v1 / keepf : 0.0f;
    h2u[(size_t)node * 32 + fl] = pk2(r0, r1);
  }
}

// ---------------- gather-aggregate layer 2 (+log_softmax) ----------------
// gs rows = 20 uints (40 bf16). Lanes fl<20 active; 2 edge slots.
__global__ __launch_bounds__(256) void k_agg2(const uint32_t* __restrict__ gsu,
                                              const int* __restrict__ elist,
                                              const int* __restrict__ offs,
                                              const float* __restrict__ dis,
                                              const float* __restrict__ b2,
                                              float* __restrict__ out) {
  const int gid = blockIdx.x * 256 + threadIdx.x;
  const int node = gid >> 6;
  const int lane = gid & 63;
  if (node >= NNODES) return;
  const int fl = lane & 31, q = lane >> 5;
  const bool act = fl < (NCLS / 2);  // 20 uint pairs
  const int base = offs[node];
  const int n = offs[node + 1] - base;
  float lo0 = 0.f, hi0 = 0.f, lo1 = 0.f, hi1 = 0.f;
  float lo2 = 0.f, hi2 = 0.f, lo3 = 0.f, hi3 = 0.f;
  if (q == 0 && act) {  // self term
    const uint32_t u = gsu[(size_t)node * 20 + fl];
    lo0 = bflo(u); hi0 = bfhi(u);
  }
  for (int k0 = 0; k0 < n; k0 += 64) {
    const int m = min(64, n - k0);
    int srcl = 0;
    if (lane < m) srcl = elist[base + k0 + lane];
    for (int j = 0; j < m; j += 8) {
      const int e0 = j + q, e1 = j + 2 + q, e2 = j + 4 + q, e3 = j + 6 + q;
      const int s0 = __shfl(srcl, e0, 64);
      const int s1 = __shfl(srcl, e1, 64);
      const int s2 = __shfl(srcl, e2, 64);
      const int s3 = __shfl(srcl, e3, 64);
      const uint32_t u0 = (act && e0 < m) ? gsu[(size_t)s0 * 20 + fl] : 0u;
      const uint32_t u1 = (act && e1 < m) ? gsu[(size_t)s1 * 20 + fl] : 0u;
      const uint32_t u2 = (act && e2 < m) ? gsu[(size_t)s2 * 20 + fl] : 0u;
      const uint32_t u3 = (act && e3 < m) ? gsu[(size_t)s3 * 20 + fl] : 0u;
      lo0 += bflo(u0); hi0 += bfhi(u0);
      lo1 += bflo(u1); hi1 += bfhi(u1);
      lo2 += bflo(u2); hi2 += bfhi(u2);
      lo3 += bflo(u3); hi3 += bfhi(u3);
    }
  }
  float alo = (lo0 + lo1) + (lo2 + lo3);
  float ahi = (hi0 + hi1) + (hi2 + hi3);
  alo += __shfl_xor(alo, 32, 64);
  ahi += __shfl_xor(ahi, 32, 64);
  // logits (both 32-lane halves hold identical totals)
  const float d = dis[node];
  const int f0 = fl * 2;
  const float l0 = act ? (alo * d + b2[f0]) : -INFINITY;
  const float l1 = act ? (ahi * d + b2[f0 + 1]) : -INFINITY;
  // log_softmax over 40 values (2 per active lane), within each 32-lane half
  float mx = fmaxf(l0, l1);
#pragma unroll
  for (int off = 16; off > 0; off >>= 1) mx = fmaxf(mx, __shfl_xor(mx, off, 64));
  float e = act ? (expf(l0 - mx) + expf(l1 - mx)) : 0.0f;
  float s = e;
#pragma unroll
  for (int off = 16; off > 0; off >>= 1) s += __shfl_xor(s, off, 64);
  const float ls = logf(s);
  if (lane < 32 && act) {
    out[(size_t)node * NCLS + f0]     = l0 - mx - ls;
    out[(size_t)node * NCLS + f0 + 1] = l1 - mx - ls;
  }
}

// ---------------- launch ----------------
extern "C" void kernel_launch(void* const* d_in, const int* in_sizes, int n_in,
                              void* d_out, int out_size, void* d_ws, size_t ws_size,
                              hipStream_t stream) {
  const float* x  = (const float*)d_in[0];
  const int*   ei = (const int*)d_in[1];
  const float* W1 = (const float*)d_in[2];
  const float* b1 = (const float*)d_in[3];
  const float* W2 = (const float*)d_in[4];
  const float* b2 = (const float*)d_in[5];
  float* out = (float*)d_out;

  const int* row = ei;           // edge_index[0]  (source)
  const int* col = ei + NEDGES;  // edge_index[1]  (destination)

  float* ws  = (float*)d_ws;
  float* dis = ws;                                   // N f32
  ushort* h1s = (ushort*)(ws + 100352);              // N*64 bf16 (12.8 MB)
  ushort* h2  = h1s + (size_t)NNODES * HID;          // N*64 bf16
  int* offs  = (int*)(h2 + (size_t)NNODES * HID);    // N+1
  int* gcur  = offs + NNODES + 64;                   // 256
  int* bbase = gcur + 256;                           // 256
  int* elist = bbase + 256;                          // E
  uint32_t* pairs = (uint32_t*)h1s;  // alias: consumed by k_csr before k_mm1
  ushort* gs = h1s;                  // alias: h1s dead after k_agg1

  const dim3 B(256);
  const int GNW = (NNODES * 64 + 255) / 256;     // wave per node
  const int GMM = (NNODES + 255) / 256;          // 64 rows/wave * 4 waves

  // CSR build (bin -> bucket scan -> per-bucket sort)
  k_initcur<<<dim3(1), B, 0, stream>>>(gcur);
  k_bin  <<<dim3(NBINBLK), B, 0, stream>>>(row, col, gcur, pairs);
  k_bscan<<<dim3(1), B, 0, stream>>>(gcur, bbase);
  k_csr  <<<dim3(NBUCK), B, 0, stream>>>(pairs, gcur, bbase, offs, dis, elist);

  // layer 1
  k_mm1 <<<dim3(GMM), B, 0, stream>>>(x, W1, dis, h1s);
  k_agg1<<<dim3(GNW), B, 0, stream>>>((const uint32_t*)h1s, elist, offs, dis, b1,
                                      (uint32_t*)h2);

  // layer 2
  k_mm2 <<<dim3(GMM), B, 0, stream>>>(h2, W2, dis, gs);
  k_agg2<<<dim3(GNW), B, 0, stream>>>((const uint32_t*)gs, elist, offs, dis, b2, out);
}

// Round 13
// 197.540 us; speedup vs baseline: 2.1272x; 1.0154x over previous
//
#include <hip/hip_runtime.h>
#include <cstdint>
#include <cstddef>

#define NNODES 100000
#define NEDGES 1600000
#define FIN    128
#define HID    64
#define NCLS   40
#define BSH    9                                   // 512 nodes per bucket
#define BNODES (1 << BSH)
#define NBUCK  ((NNODES + BNODES - 1) >> BSH)      // 196
#define EPB    8192                                // edges per k_bin block
#define NBINBLK ((NEDGES + EPB - 1) / EPB)         // 196
#define CSR_CAP 12288                              // slots per bucket

typedef __attribute__((ext_vector_type(8))) short bf16x8;
typedef __attribute__((ext_vector_type(16))) float f32x16;

// ---------------- bf16 helpers ----------------
__device__ __forceinline__ uint32_t bf16rne(float f) {
  uint32_t u = __float_as_uint(f);
  return (u + 0x7fffu + ((u >> 16) & 1u)) >> 16;
}
__device__ __forceinline__ float bflo(uint32_t u) { return __uint_as_float(u << 16); }
__device__ __forceinline__ float bfhi(uint32_t u) { return __uint_as_float(u & 0xffff0000u); }

// ---------------- Threefry-2x32 (JAX-compatible, partitionable) ----------------
__device__ __forceinline__ uint32_t rotl32(uint32_t x, uint32_t r) {
  return (x << r) | (x >> (32u - r));
}

__device__ __forceinline__ void threefry2x32(uint32_t k0, uint32_t k1,
                                             uint32_t c0, uint32_t c1,
                                             uint32_t& o0, uint32_t& o1) {
  const uint32_t ks2 = k0 ^ k1 ^ 0x1BD11BDAu;
  uint32_t x0 = c0 + k0;
  uint32_t x1 = c1 + k1;
#define TF_R(r) { x0 += x1; x1 = rotl32(x1, r); x1 ^= x0; }
  TF_R(13u) TF_R(15u) TF_R(26u) TF_R(6u)
  x0 += k1;  x1 += ks2 + 1u;
  TF_R(17u) TF_R(29u) TF_R(16u) TF_R(24u)
  x0 += ks2; x1 += k0 + 2u;
  TF_R(13u) TF_R(15u) TF_R(26u) TF_R(6u)
  x0 += k0;  x1 += k1 + 3u;
  TF_R(17u) TF_R(29u) TF_R(16u) TF_R(24u)
  x0 += k1;  x1 += ks2 + 4u;
  TF_R(13u) TF_R(15u) TF_R(26u) TF_R(6u)
  x0 += ks2; x1 += k0 + 5u;
#undef TF_R
  o0 = x0; o1 = x1;
}

// ---------------- CSR build (round-9 version, measured fine) ----------------
__global__ __launch_bounds__(256) void k_initcur(int* __restrict__ gcur) {
  gcur[threadIdx.x] = threadIdx.x * CSR_CAP;
}

__global__ __launch_bounds__(256) void k_bin(const int* __restrict__ row,
                                             const int* __restrict__ col,
                                             int* __restrict__ gcur,
                                             uint32_t* __restrict__ pairs) {
  __shared__ int hcnt[256];
  __shared__ int sc[256];
  __shared__ int lofs[256];
  __shared__ int cur2[256];
  __shared__ int gofs[256];
  __shared__ uint32_t buf[EPB];
  __shared__ unsigned char bid[EPB];
  const int t = threadIdx.x;
  const int e0 = blockIdx.x * EPB;
  const int m = min(EPB, NEDGES - e0);
  hcnt[t] = 0;
  __syncthreads();
  for (int i = t; i < m; i += 256) {
    atomicAdd(&hcnt[col[e0 + i] >> BSH], 1);
  }
  __syncthreads();
  sc[t] = hcnt[t];
  __syncthreads();
  for (int d = 1; d < 256; d <<= 1) {
    int u = (t >= d) ? sc[t - d] : 0;
    __syncthreads();
    sc[t] += u;
    __syncthreads();
  }
  const int ex = sc[t] - hcnt[t];
  lofs[t] = ex;
  cur2[t] = ex;
  if (t < NBUCK) gofs[t] = atomicAdd(&gcur[t], hcnt[t]);
  __syncthreads();
  for (int i = t; i < m; i += 256) {
    const int c = col[e0 + i];
    const int r = row[e0 + i];
    const int b = c >> BSH;
    const int p = atomicAdd(&cur2[b], 1);
    buf[p] = ((uint32_t)r << BSH) | (uint32_t)(c & (BNODES - 1));
    bid[p] = (unsigned char)b;
  }
  __syncthreads();
  for (int i = t; i < m; i += 256) {
    const int b = bid[i];
    pairs[gofs[b] + (i - lofs[b])] = buf[i];
  }
}

__global__ __launch_bounds__(256) void k_bscan(const int* __restrict__ gcur,
                                               int* __restrict__ bbase) {
  __shared__ int sc[256];
  __shared__ int cval[256];
  const int t = threadIdx.x;
  const int c = gcur[t] - t * CSR_CAP;
  cval[t] = c;
  sc[t] = c;
  __syncthreads();
  for (int d = 1; d < 256; d <<= 1) {
    int u = (t >= d) ? sc[t - d] : 0;
    __syncthreads();
    sc[t] += u;
    __syncthreads();
  }
  bbase[t] = sc[t] - cval[t];
}

__global__ __launch_bounds__(256) void k_csr(const uint32_t* __restrict__ pairs,
                                             const int* __restrict__ gcur,
                                             const int* __restrict__ bbase,
                                             int* __restrict__ offs,
                                             float* __restrict__ dis,
                                             int* __restrict__ elist) {
  __shared__ int hist[BNODES];
  __shared__ int ncur[BNODES];
  __shared__ int wsum[4];
  __shared__ int ebuf[CSR_CAP];
  const int b = blockIdx.x, t = threadIdx.x;
  const int nf = b << BSH;
  const int slot0 = b * CSR_CAP;
  const int ne = gcur[b] - slot0;
  const int base = bbase[b];
  hist[2 * t] = 0;
  hist[2 * t + 1] = 0;
  __syncthreads();
  for (int i = t; i < ne; i += 256) {
    atomicAdd(&hist[pairs[slot0 + i] & (BNODES - 1)], 1);
  }
  __syncthreads();
  const int a = hist[2 * t], c = hist[2 * t + 1];
  const int s = a + c;
  const int lane = t & 63, wid = t >> 6;
  int scv = s;
#pragma unroll
  for (int off = 1; off < 64; off <<= 1) {
    int u = __shfl_up(scv, off, 64);
    if (lane >= off) scv += u;
  }
  if (lane == 63) wsum[wid] = scv;
  __syncthreads();
  int wadd = 0;
  for (int w = 0; w < wid; ++w) wadd += wsum[w];
  const int ex = scv - s + wadd;
  const int n0 = nf + 2 * t, n1 = nf + 2 * t + 1;
  if (n0 < NNODES) {
    offs[n0] = base + ex;
    dis[n0] = rsqrtf((float)(a + 1));
  }
  if (n1 < NNODES) {
    offs[n1] = base + ex + a;
    dis[n1] = rsqrtf((float)(c + 1));
  }
  if (b == NBUCK - 1 && t == 0) offs[NNODES] = base + ne;
  ncur[2 * t] = ex;
  ncur[2 * t + 1] = ex + a;
  __syncthreads();
  for (int i = t; i < ne; i += 256) {
    const uint32_t p = pairs[slot0 + i];
    const int n = (int)(p & (BNODES - 1));
    const int sl = atomicAdd(&ncur[n], 1);
    ebuf[sl] = (int)(p >> BSH);
  }
  __syncthreads();
  for (int i = t; i < ne; i += 256) elist[base + i] = ebuf[i];
}

// ---------------- mm1 (MFMA): h1s = bf16( (x @ W1) * dis[row] ) --------------
__global__ __launch_bounds__(256) void k_mm1(const float* __restrict__ x,
                                             const float* __restrict__ W1,
                                             const float* __restrict__ dis,
                                             ushort* __restrict__ h1s) {
  __shared__ ushort wl[FIN * HID];  // W1 as bf16, row-major [128][64]
  const int t = threadIdx.x;
  for (int i = t; i < FIN * HID; i += 256) wl[i] = (ushort)bf16rne(W1[i]);
  __syncthreads();

  const int lane = t & 63;
  const int wglob = blockIdx.x * 4 + (t >> 6);
  const int r0 = wglob * 64;
  if (r0 >= NNODES) return;
  const int c0 = lane & 31;
  const int hi8 = (lane >> 5) * 8;

  bf16x8 wb0[8], wb1[8];
#pragma unroll
  for (int ks = 0; ks < 8; ++ks) {
#pragma unroll
    for (int i = 0; i < 8; ++i) {
      const int k = ks * 16 + hi8 + i;
      wb0[ks][i] = (short)wl[k * HID + c0];
      wb1[ks][i] = (short)wl[k * HID + 32 + c0];
    }
  }

  const int ra = min(r0 + c0, NNODES - 1);
  const int rb = min(r0 + 32 + c0, NNODES - 1);
  f32x16 acc00 = {0}, acc01 = {0}, acc10 = {0}, acc11 = {0};
#pragma unroll
  for (int ks = 0; ks < 8; ++ks) {
    const int k0 = ks * 16 + hi8;
    const float4 fa0 = *reinterpret_cast<const float4*>(x + (size_t)ra * FIN + k0);
    const float4 fa1 = *reinterpret_cast<const float4*>(x + (size_t)ra * FIN + k0 + 4);
    const float4 fb0 = *reinterpret_cast<const float4*>(x + (size_t)rb * FIN + k0);
    const float4 fb1 = *reinterpret_cast<const float4*>(x + (size_t)rb * FIN + k0 + 4);
    bf16x8 a0, a1;
    a0[0] = (short)bf16rne(fa0.x); a0[1] = (short)bf16rne(fa0.y);
    a0[2] = (short)bf16rne(fa0.z); a0[3] = (short)bf16rne(fa0.w);
    a0[4] = (short)bf16rne(fa1.x); a0[5] = (short)bf16rne(fa1.y);
    a0[6] = (short)bf16rne(fa1.z); a0[7] = (short)bf16rne(fa1.w);
    a1[0] = (short)bf16rne(fb0.x); a1[1] = (short)bf16rne(fb0.y);
    a1[2] = (short)bf16rne(fb0.z); a1[3] = (short)bf16rne(fb0.w);
    a1[4] = (short)bf16rne(fb1.x); a1[5] = (short)bf16rne(fb1.y);
    a1[6] = (short)bf16rne(fb1.z); a1[7] = (short)bf16rne(fb1.w);
    acc00 = __builtin_amdgcn_mfma_f32_32x32x16_bf16(a0, wb0[ks], acc00, 0, 0, 0);
    acc01 = __builtin_amdgcn_mfma_f32_32x32x16_bf16(a0, wb1[ks], acc01, 0, 0, 0);
    acc10 = __builtin_amdgcn_mfma_f32_32x32x16_bf16(a1, wb0[ks], acc10, 0, 0, 0);
    acc11 = __builtin_amdgcn_mfma_f32_32x32x16_bf16(a1, wb1[ks], acc11, 0, 0, 0);
  }

  const int rrb = 4 * (lane >> 5);
#pragma unroll
  for (int reg = 0; reg < 16; ++reg) {
    const int rr = (reg & 3) + 8 * (reg >> 2) + rrb;
    const int r_a = r0 + rr;
    const int r_b = r0 + 32 + rr;
    if (r_a < NNODES) {
      const float d = dis[r_a];
      h1s[(size_t)r_a * HID + c0]      = (ushort)bf16rne(acc00[reg] * d);
      h1s[(size_t)r_a * HID + 32 + c0] = (ushort)bf16rne(acc01[reg] * d);
    }
    if (r_b < NNODES) {
      const float d = dis[r_b];
      h1s[(size_t)r_b * HID + c0]      = (ushort)bf16rne(acc10[reg] * d);
      h1s[(size_t)r_b * HID + 32 + c0] = (ushort)bf16rne(acc11[reg] * d);
    }
  }
}

// ---------------- mm2 (MFMA): gs = bf16( (h2 @ W2pad) * dis[row] ), 64 cols --
__global__ __launch_bounds__(256) void k_mm2(const ushort* __restrict__ h2,
                                             const float* __restrict__ W2,
                                             const float* __restrict__ dis,
                                             ushort* __restrict__ gs) {
  __shared__ ushort wl[HID * 64];  // [64][64], cols >= 40 zero
  const int t = threadIdx.x;
  for (int i = t; i < HID * 64; i += 256) {
    const int k = i >> 6, c = i & 63;
    wl[i] = (c < NCLS) ? (ushort)bf16rne(W2[k * NCLS + c]) : (ushort)0;
  }
  __syncthreads();

  const int lane = t & 63;
  const int wglob = blockIdx.x * 4 + (t >> 6);
  const int r0 = wglob * 64;
  if (r0 >= NNODES) return;
  const int c0 = lane & 31;
  const int hi8 = (lane >> 5) * 8;

  bf16x8 wb0[4], wb1[4];
#pragma unroll
  for (int ks = 0; ks < 4; ++ks) {
#pragma unroll
    for (int i = 0; i < 8; ++i) {
      const int k = ks * 16 + hi8 + i;
      wb0[ks][i] = (short)wl[k * 64 + c0];
      wb1[ks][i] = (short)wl[k * 64 + 32 + c0];
    }
  }

  const int ra = min(r0 + c0, NNODES - 1);
  const int rb = min(r0 + 32 + c0, NNODES - 1);
  f32x16 acc00 = {0}, acc01 = {0}, acc10 = {0}, acc11 = {0};
#pragma unroll
  for (int ks = 0; ks < 4; ++ks) {
    const int k0 = ks * 16 + hi8;
    const bf16x8 a0 = *reinterpret_cast<const bf16x8*>(h2 + (size_t)ra * HID + k0);
    const bf16x8 a1 = *reinterpret_cast<const bf16x8*>(h2 + (size_t)rb * HID + k0);
    acc00 = __builtin_amdgcn_mfma_f32_32x32x16_bf16(a0, wb0[ks], acc00, 0, 0, 0);
    acc01 = __builtin_amdgcn_mfma_f32_32x32x16_bf16(a0, wb1[ks], acc01, 0, 0, 0);
    acc10 = __builtin_amdgcn_mfma_f32_32x32x16_bf16(a1, wb0[ks], acc10, 0, 0, 0);
    acc11 = __builtin_amdgcn_mfma_f32_32x32x16_bf16(a1, wb1[ks], acc11, 0, 0, 0);
  }

  const int rrb = 4 * (lane >> 5);
#pragma unroll
  for (int reg = 0; reg < 16; ++reg) {
    const int rr = (reg & 3) + 8 * (reg >> 2) + rrb;
    const int r_a = r0 + rr;
    const int r_b = r0 + 32 + rr;
    if (r_a < NNODES) {
      const float d = dis[r_a];
      gs[(size_t)r_a * 64 + c0]      = (ushort)bf16rne(acc00[reg] * d);
      gs[(size_t)r_a * 64 + 32 + c0] = (ushort)bf16rne(acc01[reg] * d);  // cols>=40 are 0
    }
    if (r_b < NNODES) {
      const float d = dis[r_b];
      gs[(size_t)r_b * 64 + c0]      = (ushort)bf16rne(acc10[reg] * d);
      gs[(size_t)r_b * 64 + 32 + c0] = (ushort)bf16rne(acc11[reg] * d);
    }
  }
}

// ---------------- gather-aggregate layer 1: uint4 row loads, 8 edge slots ----
// lane = q*8+fl: q=lane>>3 edge slot, fl=lane&7 -> 16B chunk (8 bf16) of row.
__global__ __launch_bounds__(256) void k_agg1(const uint32_t* __restrict__ h1u,
                                              const int* __restrict__ elist,
                                              const int* __restrict__ offs,
                                              const float* __restrict__ dis,
                                              const float* __restrict__ b1,
                                              ushort* __restrict__ h2s) {
  const int gid = blockIdx.x * 256 + threadIdx.x;
  const int node = gid >> 6;       // grid exact: node < NNODES always
  const int lane = gid & 63;
  const int q = lane >> 3, fl = lane & 7;
  const int base = offs[node];
  const int n = offs[node + 1] - base;
  float a0 = 0.f, a1 = 0.f, a2 = 0.f, a3 = 0.f, a4 = 0.f, a5 = 0.f, a6 = 0.f, a7 = 0.f;
  if (q == 0) {  // self term
    const uint4 u = *reinterpret_cast<const uint4*>(h1u + (size_t)node * 32 + fl * 4);
    a0 = bflo(u.x); a1 = bfhi(u.x); a2 = bflo(u.y); a3 = bfhi(u.y);
    a4 = bflo(u.z); a5 = bfhi(u.z); a6 = bflo(u.w); a7 = bfhi(u.w);
  }
  for (int k0 = 0; k0 < n; k0 += 64) {
    const int m = min(64, n - k0);
    int srcl = 0;
    if (lane < m) srcl = elist[base + k0 + lane];
    for (int j = 0; j < m; j += 8) {
      const int e = j + q;
      const int s = __shfl(srcl, e, 64);
      if (e < m) {
        const uint4 u = *reinterpret_cast<const uint4*>(h1u + (size_t)s * 32 + fl * 4);
        a0 += bflo(u.x); a1 += bfhi(u.x); a2 += bflo(u.y); a3 += bfhi(u.y);
        a4 += bflo(u.z); a5 += bfhi(u.z); a6 += bflo(u.w); a7 += bfhi(u.w);
      }
    }
  }
  // reduce across the 8 slots (bits 3..5 of lane)
#pragma unroll
  for (int off = 8; off < 64; off <<= 1) {
    a0 += __shfl_xor(a0, off, 64); a1 += __shfl_xor(a1, off, 64);
    a2 += __shfl_xor(a2, off, 64); a3 += __shfl_xor(a3, off, 64);
    a4 += __shfl_xor(a4, off, 64); a5 += __shfl_xor(a5, off, 64);
    a6 += __shfl_xor(a6, off, 64); a7 += __shfl_xor(a7, off, 64);
  }
  // transpose: lane f wants element (f&7) from any lane with fl == f>>3
  const int sl = lane >> 3;
  const float v0 = __shfl(a0, sl, 64), v1 = __shfl(a1, sl, 64);
  const float v2 = __shfl(a2, sl, 64), v3 = __shfl(a3, sl, 64);
  const float v4 = __shfl(a4, sl, 64), v5 = __shfl(a5, sl, 64);
  const float v6 = __shfl(a6, sl, 64), v7 = __shfl(a7, sl, 64);
  const int ss = lane & 7;
  float val = (ss == 0) ? v0 : (ss == 1) ? v1 : (ss == 2) ? v2 : (ss == 3) ? v3
            : (ss == 4) ? v4 : (ss == 5) ? v5 : (ss == 6) ? v6 : v7;
  // epilogue: bias + relu + dropout, one threefry per lane
  float v = fmaxf(val * dis[node] + b1[lane], 0.0f);
  uint32_t o0, o1;
  threefry2x32(0u, 42u, 0u, (uint32_t)node * HID + lane, o0, o1);
  const uint32_t bits = o0 ^ o1;
  const float u = __uint_as_float((bits >> 9) | 0x3f800000u) - 1.0f;
  const float keepf = (float)(1.0 - 0.4144);
  const float r = (u < keepf) ? v / keepf : 0.0f;
  h2s[(size_t)node * HID + lane] = (ushort)bf16rne(r);
}

// ---------------- gather-aggregate layer 2 (+log_softmax), padded 64 cols ----
__global__ __launch_bounds__(256) void k_agg2(const uint32_t* __restrict__ gsu,
                                              const int* __restrict__ elist,
                                              const int* __restrict__ offs,
                                              const float* __restrict__ dis,
                                              const float* __restrict__ b2,
                                              float* __restrict__ out) {
  const int gid = blockIdx.x * 256 + threadIdx.x;
  const int node = gid >> 6;
  const int lane = gid & 63;
  const int q = lane >> 3, fl = lane & 7;
  const int base = offs[node];
  const int n = offs[node + 1] - base;
  float a0 = 0.f, a1 = 0.f, a2 = 0.f, a3 = 0.f, a4 = 0.f, a5 = 0.f, a6 = 0.f, a7 = 0.f;
  if (q == 0) {  // self term
    const uint4 u = *reinterpret_cast<const uint4*>(gsu + (size_t)node * 32 + fl * 4);
    a0 = bflo(u.x); a1 = bfhi(u.x); a2 = bflo(u.y); a3 = bfhi(u.y);
    a4 = bflo(u.z); a5 = bfhi(u.z); a6 = bflo(u.w); a7 = bfhi(u.w);
  }
  for (int k0 = 0; k0 < n; k0 += 64) {
    const int m = min(64, n - k0);
    int srcl = 0;
    if (lane < m) srcl = elist[base + k0 + lane];
    for (int j = 0; j < m; j += 8) {
      const int e = j + q;
      const int s = __shfl(srcl, e, 64);
      if (e < m) {
        const uint4 u = *reinterpret_cast<const uint4*>(gsu + (size_t)s * 32 + fl * 4);
        a0 += bflo(u.x); a1 += bfhi(u.x); a2 += bflo(u.y); a3 += bfhi(u.y);
        a4 += bflo(u.z); a5 += bfhi(u.z); a6 += bflo(u.w); a7 += bfhi(u.w);
      }
    }
  }
#pragma unroll
  for (int off = 8; off < 64; off <<= 1) {
    a0 += __shfl_xor(a0, off, 64); a1 += __shfl_xor(a1, off, 64);
    a2 += __shfl_xor(a2, off, 64); a3 += __shfl_xor(a3, off, 64);
    a4 += __shfl_xor(a4, off, 64); a5 += __shfl_xor(a5, off, 64);
    a6 += __shfl_xor(a6, off, 64); a7 += __shfl_xor(a7, off, 64);
  }
  const int sl = lane >> 3;
  const float v0 = __shfl(a0, sl, 64), v1 = __shfl(a1, sl, 64);
  const float v2 = __shfl(a2, sl, 64), v3 = __shfl(a3, sl, 64);
  const float v4 = __shfl(a4, sl, 64), v5 = __shfl(a5, sl, 64);
  const float v6 = __shfl(a6, sl, 64), v7 = __shfl(a7, sl, 64);
  const int ss = lane & 7;
  float val = (ss == 0) ? v0 : (ss == 1) ? v1 : (ss == 2) ? v2 : (ss == 3) ? v3
            : (ss == 4) ? v4 : (ss == 5) ? v5 : (ss == 6) ? v6 : v7;
  // logits + log_softmax over 40 classes (lanes >= 40 are pad)
  const bool act = lane < NCLS;
  const float l = act ? (val * dis[node] + b2[lane]) : -INFINITY;
  float mx = l;
#pragma unroll
  for (int off = 32; off > 0; off >>= 1) mx = fmaxf(mx, __shfl_xor(mx, off, 64));
  float e = act ? expf(l - mx) : 0.0f;
  float s = e;
#pragma unroll
  for (int off = 32; off > 0; off >>= 1) s += __shfl_xor(s, off, 64);
  const float ls = logf(s);
  if (act) out[(size_t)node * NCLS + lane] = l - mx - ls;
}

// ---------------- launch ----------------
extern "C" void kernel_launch(void* const* d_in, const int* in_sizes, int n_in,
                              void* d_out, int out_size, void* d_ws, size_t ws_size,
                              hipStream_t stream) {
  const float* x  = (const float*)d_in[0];
  const int*   ei = (const int*)d_in[1];
  const float* W1 = (const float*)d_in[2];
  const float* b1 = (const float*)d_in[3];
  const float* W2 = (const float*)d_in[4];
  const float* b2 = (const float*)d_in[5];
  float* out = (float*)d_out;

  const int* row = ei;           // edge_index[0]  (source)
  const int* col = ei + NEDGES;  // edge_index[1]  (destination)

  float* ws  = (float*)d_ws;
  float* dis = ws;                                   // N f32
  ushort* h1s = (ushort*)(ws + 100352);              // N*64 bf16 (12.8 MB)
  ushort* h2  = h1s + (size_t)NNODES * HID;          // N*64 bf16
  int* offs  = (int*)(h2 + (size_t)NNODES * HID);    // N+1
  int* gcur  = offs + NNODES + 64;                   // 256
  int* bbase = gcur + 256;                           // 256
  int* elist = bbase + 256;                          // E
  uint32_t* pairs = (uint32_t*)h1s;  // alias: consumed by k_csr before k_mm1
  ushort* gs = h1s;                  // alias: h1s dead after k_agg1 (N*64 padded)

  const dim3 B(256);
  const int GNW = (NNODES * 64) / 256;           // 25000, exact
  const int GMM = (NNODES + 255) / 256;          // 64 rows/wave * 4 waves

  // CSR build (bin -> bucket scan -> per-bucket sort)
  k_initcur<<<dim3(1), B, 0, stream>>>(gcur);
  k_bin  <<<dim3(NBINBLK), B, 0, stream>>>(row, col, gcur, pairs);
  k_bscan<<<dim3(1), B, 0, stream>>>(gcur, bbase);
  k_csr  <<<dim3(NBUCK), B, 0, stream>>>(pairs, gcur, bbase, offs, dis, elist);

  // layer 1
  k_mm1 <<<dim3(GMM), B, 0, stream>>>(x, W1, dis, h1s);
  k_agg1<<<dim3(GNW), B, 0, stream>>>((const uint32_t*)h1s, elist, offs, dis, b1, h2);

  // layer 2
  k_mm2 <<<dim3(GMM), B, 0, stream>>>(h2, W2, dis, gs);
  k_agg2<<<dim3(GNW), B, 0, stream>>>((const uint32_t*)gs, elist, offs, dis, b2, out);
}